// Round 1
// baseline (598.965 us; speedup 1.0000x reference)
//
#include <hip/hip_runtime.h>
#include <hip/hip_bf16.h>

#define NB 2
#define NS 512
#define ND 1024
#define NH 8
#define NDK 128
#define NDFF 4096
#define RPAD 64
#define BSROWS (NB * NS)      /* 1024 */
#define BHS (NB * NH * NS)    /* 8192 */

typedef __bf16 bf16x8 __attribute__((ext_vector_type(8)));
typedef float f32x4 __attribute__((ext_vector_type(4)));

// ---------------------------------------------------------------------------
// Generic bf16 MFMA GEMM: C[M,N] = A[M,K] @ Bt[N,K]^T (+bias, +resid, relu,
// accumulate, bf16-out). 128x128 tile, BK=32, 4 waves, 16x16x32 MFMA.
// Batched via blockIdx.z with element strides sA/sB/sC.
// ---------------------------------------------------------------------------
#define BM 128
#define BN 128
#define BKK 32
#define LDP 40  /* padded LDS row stride (bf16): 80B, 16B-aligned, ~2-way banks */

__global__ __launch_bounds__(256) void gemm_bf16(
    const __bf16* __restrict__ A, const __bf16* __restrict__ Bt,
    float* __restrict__ Cf, __bf16* __restrict__ Cb,
    const float* __restrict__ bias, const float* __restrict__ resid,
    int M, int N, int K, int lda, int ldb, int ldc,
    long sA, long sB, long sC, int flags)
{
    __shared__ __bf16 As[BM * LDP];
    __shared__ __bf16 Bs[BN * LDP];

    const int z = blockIdx.z;
    A += (long)z * sA;
    Bt += (long)z * sB;
    const long coff = (long)z * sC;

    const int tM = blockIdx.y * BM;
    const int tN = blockIdx.x * BN;
    const int t = threadIdx.x;
    const int lane = t & 63;
    const int w = t >> 6;
    const int wr = w >> 1;
    const int wc = w & 1;

    f32x4 acc[4][4];
#pragma unroll
    for (int m = 0; m < 4; ++m)
#pragma unroll
        for (int n = 0; n < 4; ++n)
#pragma unroll
            for (int j = 0; j < 4; ++j) acc[m][n][j] = 0.f;

    for (int k0 = 0; k0 < K; k0 += BKK) {
        // stage A-tile [128][32] and Bt-tile [128][32] (reg-staged, zero-fill OOB)
#pragma unroll
        for (int it = 0; it < 2; ++it) {
            const int o = t + it * 256;   // 0..511
            const int row = o >> 2;       // 0..127
            const int col = (o & 3) * 8;  // 0,8,16,24
            bf16x8 v;
#pragma unroll
            for (int q = 0; q < 8; ++q) v[q] = (__bf16)0.f;
            const int gr = tM + row;
            if (gr < M) v = *reinterpret_cast<const bf16x8*>(A + (long)gr * lda + k0 + col);
            *reinterpret_cast<bf16x8*>(&As[row * LDP + col]) = v;

            bf16x8 u;
#pragma unroll
            for (int q = 0; q < 8; ++q) u[q] = (__bf16)0.f;
            const int gn = tN + row;
            if (gn < N) u = *reinterpret_cast<const bf16x8*>(Bt + (long)gn * ldb + k0 + col);
            *reinterpret_cast<bf16x8*>(&Bs[row * LDP + col]) = u;
        }
        __syncthreads();

        const int kb = (lane >> 4) * 8;
        const int r16 = lane & 15;
        bf16x8 af[4], bfr[4];
#pragma unroll
        for (int m = 0; m < 4; ++m)
            af[m] = *reinterpret_cast<const bf16x8*>(&As[(wr * 64 + m * 16 + r16) * LDP + kb]);
#pragma unroll
        for (int n = 0; n < 4; ++n)
            bfr[n] = *reinterpret_cast<const bf16x8*>(&Bs[(wc * 64 + n * 16 + r16) * LDP + kb]);
#pragma unroll
        for (int m = 0; m < 4; ++m)
#pragma unroll
            for (int n = 0; n < 4; ++n)
                acc[m][n] = __builtin_amdgcn_mfma_f32_16x16x32_bf16(af[m], bfr[n], acc[m][n], 0, 0, 0);
        __syncthreads();
    }

    const bool relu = (flags & 1) != 0;
    const bool accum = (flags & 2) != 0;
#pragma unroll
    for (int m = 0; m < 4; ++m) {
        const int grow0 = tM + wr * 64 + m * 16 + (lane >> 4) * 4;
#pragma unroll
        for (int n = 0; n < 4; ++n) {
            const int gcol = tN + wc * 64 + n * 16 + (lane & 15);
            if (gcol >= N) continue;
            const float bv = bias ? bias[gcol] : 0.f;
#pragma unroll
            for (int j = 0; j < 4; ++j) {
                const int grow = grow0 + j;
                if (grow >= M) continue;
                float val = acc[m][n][j] + bv;
                const long idx = coff + (long)grow * ldc + gcol;
                if (resid) val += resid[idx];
                if (relu) val = fmaxf(val, 0.f);
                if (accum) val += Cf[idx];
                if (Cb) Cb[idx] = (__bf16)val;
                else Cf[idx] = val;
            }
        }
    }
}

// ---------------------------------------------------------------------------
// LayerNorm over D=1024, one block per row, output bf16.
// ---------------------------------------------------------------------------
__global__ __launch_bounds__(256) void ln_bf16(
    const float* __restrict__ x, const float* __restrict__ g,
    const float* __restrict__ bb, __bf16* __restrict__ out)
{
    const long row = blockIdx.x;
    const float* xr = x + row * ND;
    __bf16* orow = out + row * ND;
    const int t = threadIdx.x;
    float4 v = reinterpret_cast<const float4*>(xr)[t];
    float s = v.x + v.y + v.z + v.w;
    float s2 = v.x * v.x + v.y * v.y + v.z * v.z + v.w * v.w;
#pragma unroll
    for (int o = 32; o > 0; o >>= 1) {
        s += __shfl_xor(s, o, 64);
        s2 += __shfl_xor(s2, o, 64);
    }
    __shared__ float red[8];
    const int lane = t & 63, wv = t >> 6;
    if (lane == 0) { red[wv] = s; red[4 + wv] = s2; }
    __syncthreads();
    s = red[0] + red[1] + red[2] + red[3];
    s2 = red[4] + red[5] + red[6] + red[7];
    const float mean = s * (1.f / ND);
    const float var = s2 * (1.f / ND) - mean * mean;
    const float rs = rsqrtf(var + 1e-5f);
    const float xv[4] = {v.x, v.y, v.z, v.w};
#pragma unroll
    for (int j = 0; j < 4; ++j) {
        const int c = t * 4 + j;
        orow[c] = (__bf16)((xv[j] - mean) * rs * g[c] + bb[c]);
    }
}

// ---------------------------------------------------------------------------
// Tiled transpose + fp32->bf16: out[n*ldo + k] = in[k*cols_in + n], zero-pad k.
// block (32,8), grid (ceil(ldo/32), ceil(cols_in/32))
// ---------------------------------------------------------------------------
__global__ void transpose_conv(const float* __restrict__ in, __bf16* __restrict__ out,
                               int rows_in, int cols_in, int ldo)
{
    __shared__ float tile[32][33];
    const int k0 = blockIdx.x * 32;
    const int n0 = blockIdx.y * 32;
    const int tx = threadIdx.x, ty = threadIdx.y;
#pragma unroll
    for (int dy = 0; dy < 32; dy += 8) {
        const int k = k0 + ty + dy, n = n0 + tx;
        tile[ty + dy][tx] = (k < rows_in && n < cols_in) ? in[(long)k * cols_in + n] : 0.f;
    }
    __syncthreads();
#pragma unroll
    for (int dy = 0; dy < 32; dy += 8) {
        const int n = n0 + ty + dy, k = k0 + tx;
        if (n < cols_in && k < ldo) out[(long)n * ldo + k] = (__bf16)tile[tx][ty + dy];
    }
}

// rel_k_emb [R,128] fp32 -> [64,128] bf16 zero-padded
__global__ void convert_pad_relk(const float* __restrict__ in, __bf16* __restrict__ out, int R)
{
    const int idx = blockIdx.x * 256 + threadIdx.x;
    if (idx >= RPAD * NDK) return;
    const int r = idx / NDK;
    out[idx] = (r < R) ? (__bf16)in[idx] : (__bf16)0.f;
}

__global__ void pack_bias(const float* __restrict__ bq, const float* __restrict__ bk,
                          const float* __restrict__ bv, float* __restrict__ out)
{
    const int t = blockIdx.x * 256 + threadIdx.x;
    if (t < ND) out[t] = bq[t];
    else if (t < 2 * ND) out[t] = bk[t - ND];
    else if (t < 3 * ND) out[t] = bv[t - 2 * ND];
}

// qkv fp32 [BS,3D] -> q,k bf16 [B,H,S,DK]; v -> vt bf16 [B,H,DK,S]; zero loss
__global__ void split_qkv(const float* __restrict__ qkv, __bf16* __restrict__ q,
                          __bf16* __restrict__ k, __bf16* __restrict__ vt,
                          float* __restrict__ loss_ws)
{
    const int idx = blockIdx.x * 256 + threadIdx.x;
    if (idx == 0) loss_ws[0] = 0.f;
    if (idx >= NB * NH * NS * NDK) return;
    const int d = idx & (NDK - 1);
    const int i = (idx >> 7) & (NS - 1);
    const int h = (idx >> 16) & (NH - 1);
    const int b = idx >> 19;
    const long src = ((long)(b * NS + i)) * (3 * ND) + h * NDK + d;
    q[idx] = (__bf16)qkv[src];
    k[idx] = (__bf16)qkv[src + ND];
    vt[(((long)(b * NH + h)) * NDK + d) * NS + i] = (__bf16)qkv[src + 2 * ND];
}

// ctx fp32 [B,H,S,DK] -> ctxm bf16 [B,S,D]
__global__ void merge_heads(const float* __restrict__ ctx, __bf16* __restrict__ ctxm)
{
    const int idx = blockIdx.x * 256 + threadIdx.x;
    if (idx >= NB * NH * NS * NDK) return;
    const int d = idx & (NDK - 1);
    const int i = (idx >> 7) & (NS - 1);
    const int h = (idx >> 16) & (NH - 1);
    const int b = idx >> 19;
    ctxm[((long)(b * NS + i)) * ND + h * NDK + d] = (__bf16)ctx[idx];
}

// ---------------------------------------------------------------------------
// Fused: scores = (qk + qr[rel])/sqrt(DK), mask, softmax, attn->bf16,
// attnR binning (LDS atomics), loss partial (j < sep).
// grid (S, H, B), block 256 (each thread handles j=t and j=t+256)
// ---------------------------------------------------------------------------
__global__ __launch_bounds__(256) void softmax_rel(
    const float* __restrict__ scores, const float* __restrict__ qr,
    const int* __restrict__ relation, const int* __restrict__ mask,
    __bf16* __restrict__ attn, __bf16* __restrict__ attnR,
    float* __restrict__ loss_acc, const int* __restrict__ sep_p)
{
    const int i = blockIdx.x, h = blockIdx.y, b = blockIdx.z;
    const long bh = (long)(b * NH + h);
    const float* srow = scores + (bh * NS + i) * NS;
    const float* qrow = qr + (bh * NS + i) * RPAD;
    const int* rrow = relation + ((long)b * NS + i) * NS;
    const int* mrow = mask + ((long)b * NS + i) * NS;
    __bf16* arow = attn + (bh * NS + i) * NS;
    __bf16* aRrow = attnR + (bh * NS + i) * RPAD;

    __shared__ float qrl[RPAD];
    __shared__ float bins[RPAD];
    __shared__ float red[4];

    const int t = threadIdx.x;
    if (t < RPAD) { qrl[t] = qrow[t]; bins[t] = 0.f; }
    __syncthreads();

    const float sc = 0.088388347648318447f;  // 1/sqrt(128)
    const int r0 = rrow[t], r1 = rrow[t + 256];
    float v0 = (srow[t] + qrl[r0]) * sc;
    float v1 = (srow[t + 256] + qrl[r1]) * sc;
    if (mrow[t] == 0) v0 = -1e9f;
    if (mrow[t + 256] == 0) v1 = -1e9f;

    const int lane = t & 63, wv = t >> 6;

    float mx = fmaxf(v0, v1);
#pragma unroll
    for (int o = 32; o > 0; o >>= 1) mx = fmaxf(mx, __shfl_xor(mx, o, 64));
    if (lane == 0) red[wv] = mx;
    __syncthreads();
    mx = fmaxf(fmaxf(red[0], red[1]), fmaxf(red[2], red[3]));
    __syncthreads();

    const float e0 = __expf(v0 - mx), e1 = __expf(v1 - mx);
    float sm = e0 + e1;
#pragma unroll
    for (int o = 32; o > 0; o >>= 1) sm += __shfl_xor(sm, o, 64);
    if (lane == 0) red[wv] = sm;
    __syncthreads();
    sm = red[0] + red[1] + red[2] + red[3];
    __syncthreads();

    const float inv = 1.f / sm;
    const float a0 = e0 * inv, a1 = e1 * inv;
    arow[t] = (__bf16)a0;
    arow[t + 256] = (__bf16)a1;
    atomicAdd(&bins[r0], a0);
    atomicAdd(&bins[r1], a1);

    const int sep = *sep_p;
    float ls = 0.f;
    if (t < sep) ls += a0;
    if (t + 256 < sep) ls += a1;
#pragma unroll
    for (int o = 32; o > 0; o >>= 1) ls += __shfl_xor(ls, o, 64);
    if (lane == 0) red[wv] = ls;
    __syncthreads();  // also fences bins atomics
    if (t == 0) atomicAdd(loss_acc, red[0] + red[1] + red[2] + red[3]);
    if (t < RPAD) aRrow[t] = (__bf16)bins[t];
}

__global__ void finalize_loss(const float* __restrict__ loss_ws,
                              const float* __restrict__ hist,
                              const int* __restrict__ sep_p,
                              float* __restrict__ out_loss)
{
    const int sep = *sep_p;
    const float denom = (float)NB * NH * NS * (float)(sep > 0 ? sep : 1);
    out_loss[0] = (sep > 0) ? hist[0] * loss_ws[0] / denom : 0.f;
}

// ---------------------------------------------------------------------------
static inline int cdiv(int a, int b) { return (a + b - 1) / b; }

extern "C" void kernel_launch(void* const* d_in, const int* in_sizes, int n_in,
                              void* d_out, int out_size, void* d_ws, size_t ws_size,
                              hipStream_t stream)
{
    const float* x      = (const float*)d_in[0];
    const int* relation = (const int*)d_in[1];
    const int* mask     = (const int*)d_in[2];
    const int* sep_p    = (const int*)d_in[3];
    const float* hist   = (const float*)d_in[4];
    const float* Wq = (const float*)d_in[5],  *bq = (const float*)d_in[6];
    const float* Wk = (const float*)d_in[7],  *bk = (const float*)d_in[8];
    const float* Wv = (const float*)d_in[9],  *bv = (const float*)d_in[10];
    const float* Wo = (const float*)d_in[11], *bo = (const float*)d_in[12];
    const float* relk = (const float*)d_in[13];
    const float* relv = (const float*)d_in[14];
    const float* ln1g = (const float*)d_in[15], *ln1b = (const float*)d_in[16];
    const float* ln2g = (const float*)d_in[17], *ln2b = (const float*)d_in[18];
    const float* W1 = (const float*)d_in[19], *b1 = (const float*)d_in[20];
    const float* W2 = (const float*)d_in[21], *b2 = (const float*)d_in[22];
    const int R = in_sizes[13] / NDK;  // 51

    float* out = (float*)d_out;
    float* out_loss = out + (long)NB * NS * ND;

    // workspace carve-up (256B aligned)
    char* p = (char*)d_ws;
    auto alloc = [&](size_t bytes) -> void* {
        void* r = (void*)p;
        p += (bytes + 255) & ~(size_t)255;
        return r;
    };
    __bf16* h1      = (__bf16*)alloc((size_t)BSROWS * ND * 2);
    __bf16* WqkvT   = (__bf16*)alloc((size_t)3 * ND * ND * 2);
    __bf16* WoT     = (__bf16*)alloc((size_t)ND * ND * 2);
    __bf16* W1T     = (__bf16*)alloc((size_t)NDFF * ND * 2);
    __bf16* W2T     = (__bf16*)alloc((size_t)ND * NDFF * 2);
    __bf16* relkT   = (__bf16*)alloc((size_t)RPAD * NDK * 2);
    __bf16* relvT   = (__bf16*)alloc((size_t)NDK * RPAD * 2);
    float*  biasqkv = (float*)alloc((size_t)3 * ND * 4);
    float*  qkv     = (float*)alloc((size_t)BSROWS * 3 * ND * 4);
    __bf16* qb      = (__bf16*)alloc((size_t)BHS * NDK * 2);
    __bf16* kb      = (__bf16*)alloc((size_t)BHS * NDK * 2);
    __bf16* vt      = (__bf16*)alloc((size_t)BHS * NDK * 2);
    float*  qr      = (float*)alloc((size_t)BHS * RPAD * 4);
    float*  scoresb = (float*)alloc((size_t)BHS * NS * 4);
    __bf16* attnb   = (__bf16*)alloc((size_t)BHS * NS * 2);
    __bf16* attnR   = (__bf16*)alloc((size_t)BHS * RPAD * 2);
    float*  ctx     = (float*)alloc((size_t)BHS * NDK * 4);
    __bf16* ctxm    = (__bf16*)alloc((size_t)BSROWS * ND * 2);
    __bf16* h2      = (__bf16*)alloc((size_t)BSROWS * ND * 2);
    __bf16* F1      = (__bf16*)alloc((size_t)BSROWS * NDFF * 2);
    float*  loss_ws = (float*)alloc(256);

    const dim3 tb(32, 8);
    // weight transposes -> bf16 [N,K]
    transpose_conv<<<dim3(32, 32), tb, 0, stream>>>(Wq, WqkvT, ND, ND, ND);
    transpose_conv<<<dim3(32, 32), tb, 0, stream>>>(Wk, WqkvT + (size_t)ND * ND, ND, ND, ND);
    transpose_conv<<<dim3(32, 32), tb, 0, stream>>>(Wv, WqkvT + (size_t)2 * ND * ND, ND, ND, ND);
    transpose_conv<<<dim3(32, 32), tb, 0, stream>>>(Wo, WoT, ND, ND, ND);
    transpose_conv<<<dim3(32, 128), tb, 0, stream>>>(W1, W1T, ND, NDFF, ND);
    transpose_conv<<<dim3(128, 32), tb, 0, stream>>>(W2, W2T, NDFF, ND, NDFF);
    transpose_conv<<<dim3(2, 4), tb, 0, stream>>>(relv, relvT, R, NDK, RPAD);
    convert_pad_relk<<<32, 256, 0, stream>>>(relk, relkT, R);
    pack_bias<<<12, 256, 0, stream>>>(bq, bk, bv, biasqkv);

    // LN1
    ln_bf16<<<BSROWS, 256, 0, stream>>>(x, ln1g, ln1b, h1);

    // QKV fused GEMM: [1024,1024] @ [1024,3072]
    gemm_bf16<<<dim3(cdiv(3 * ND, BN), cdiv(BSROWS, BM), 1), 256, 0, stream>>>(
        h1, WqkvT, qkv, nullptr, biasqkv, nullptr,
        BSROWS, 3 * ND, ND, ND, ND, 3 * ND, 0, 0, 0, 0);

    split_qkv<<<cdiv(NB * NH * NS * NDK, 256), 256, 0, stream>>>(qkv, qb, kb, vt, loss_ws);

    // qr[b,h,i,r] = q . rel_k  (batched over 16 heads)
    gemm_bf16<<<dim3(1, cdiv(NS, BM), NB * NH), 256, 0, stream>>>(
        qb, relkT, qr, nullptr, nullptr, nullptr,
        NS, RPAD, NDK, NDK, NDK, RPAD,
        (long)NS * NDK, 0, (long)NS * RPAD, 0);

    // scores = q @ k^T (batched)
    gemm_bf16<<<dim3(cdiv(NS, BN), cdiv(NS, BM), NB * NH), 256, 0, stream>>>(
        qb, kb, scoresb, nullptr, nullptr, nullptr,
        NS, NS, NDK, NDK, NDK, NS,
        (long)NS * NDK, (long)NS * NDK, (long)NS * NS, 0);

    softmax_rel<<<dim3(NS, NH, NB), 256, 0, stream>>>(
        scoresb, qr, relation, mask, attnb, attnR, loss_ws, sep_p);

    // ctx = attn @ v (batched; vt is [DK,S] per head)
    gemm_bf16<<<dim3(1, cdiv(NS, BM), NB * NH), 256, 0, stream>>>(
        attnb, vt, ctx, nullptr, nullptr, nullptr,
        NS, NDK, NS, NS, NS, NDK,
        (long)NS * NS, (long)NDK * NS, (long)NS * NDK, 0);

    // ctx += attnR @ rel_v (accumulate)
    gemm_bf16<<<dim3(1, cdiv(NS, BM), NB * NH), 256, 0, stream>>>(
        attnR, relvT, ctx, nullptr, nullptr, nullptr,
        NS, NDK, RPAD, RPAD, RPAD, NDK,
        (long)NS * RPAD, 0, (long)NS * NDK, 2);

    merge_heads<<<cdiv(NB * NH * NS * NDK, 256), 256, 0, stream>>>(ctx, ctxm);

    // attn_out = ctxm @ Wo + bo + x  -> out (fp32)
    gemm_bf16<<<dim3(cdiv(ND, BN), cdiv(BSROWS, BM), 1), 256, 0, stream>>>(
        ctxm, WoT, out, nullptr, bo, x,
        BSROWS, ND, ND, ND, ND, ND, 0, 0, 0, 0);

    // LN2 on out
    ln_bf16<<<BSROWS, 256, 0, stream>>>(out, ln2g, ln2b, h2);

    // FFN1: relu(h2 @ W1 + b1) -> bf16
    gemm_bf16<<<dim3(cdiv(NDFF, BN), cdiv(BSROWS, BM), 1), 256, 0, stream>>>(
        h2, W1T, nullptr, F1, b1, nullptr,
        BSROWS, NDFF, ND, ND, ND, NDFF, 0, 0, 0, 1);

    // FFN2: out += F1 @ W2 + b2
    gemm_bf16<<<dim3(cdiv(ND, BN), cdiv(BSROWS, BM), 1), 256, 0, stream>>>(
        F1, W2T, out, nullptr, b2, nullptr,
        BSROWS, ND, NDFF, NDFF, NDFF, ND, 0, 0, 0, 2);

    finalize_loss<<<1, 1, 0, stream>>>(loss_ws, hist, sep_p, out_loss);
}

// Round 2
// 312.025 us; speedup vs baseline: 1.9196x; 1.9196x over previous
//
#include <hip/hip_runtime.h>
#include <hip/hip_bf16.h>

#define NB 2
#define NS 512
#define ND 1024
#define NH 8
#define NDK 128
#define NDFF 4096
#define QRLD 128
#define RPAD 64
#define BSROWS 1024           /* B*S */
#define NBH 16                /* B*H */

typedef __bf16 bf16x8 __attribute__((ext_vector_type(8)));
typedef float f32x4 __attribute__((ext_vector_type(4)));

#define BM 128
#define BN 128
#define BK 64

__device__ __forceinline__ void gload16(const void* g, void* l) {
    __builtin_amdgcn_global_load_lds(
        (const __attribute__((address_space(1))) void*)g,
        (__attribute__((address_space(3))) void*)l, 16, 0, 0);
}

// ---------------------------------------------------------------------------
// m97-structure GEMM: C[M,N] = A[M,K] @ Bt[N,K]^T. 128x128 tile, BK=64,
// 4 waves (each 64x64 via 4x4 16x16x32 MFMA), global_load_lds staging.
// Requires M,N multiples of 128, Ksp multiple of 64, 16B-aligned rows.
// Batch via z: bh = z/nsplit, sp = z%nsplit; K-window = [sp*Ksp, (sp+1)*Ksp).
// A offset = (bh/zdivA)*sA + (bh%zdivA)*sA2 (lets us address per-head column
// slices of the packed qkv buffer without copies).
// ---------------------------------------------------------------------------
__global__ __launch_bounds__(256) void gemm128(
    const __bf16* __restrict__ A, const __bf16* __restrict__ Bt,
    float* __restrict__ Cf, __bf16* __restrict__ Cb,
    const float* __restrict__ bias,
    int Ksp, int lda, int ldb, int ldc,
    long sA, long sA2, int zdivA,
    long sB, long sB2, int zdivB,
    long sC, int nsplit, long sPart, int flags)
{
    __shared__ __bf16 As[BM * BK];
    __shared__ __bf16 Bs[BN * BK];

    const int z = blockIdx.z;
    const int bh = z / nsplit, sp = z - bh * nsplit;
    const long kbase = (long)sp * Ksp;
    A  += (long)(bh / zdivA) * sA + (long)(bh % zdivA) * sA2 + kbase;
    Bt += (long)(bh / zdivB) * sB + (long)(bh % zdivB) * sB2 + kbase;
    const long cbase = (long)bh * sC + (long)sp * sPart;

    const int tM = blockIdx.y * BM, tN = blockIdx.x * BN;
    const int t = threadIdx.x, lane = t & 63, w = t >> 6;
    const int wr = w >> 1, wc = w & 1;
    const int srow = lane >> 3;          // 0..7 within 8-row chunk
    const int scol = (lane & 7) * 8;     // element col within BK

    const __bf16* gA = A + (long)(tM + srow) * lda + scol;
    const __bf16* gB = Bt + (long)(tN + srow) * ldb + scol;

    f32x4 acc[4][4];
#pragma unroll
    for (int m = 0; m < 4; ++m)
#pragma unroll
        for (int n = 0; n < 4; ++n)
#pragma unroll
            for (int j = 0; j < 4; ++j) acc[m][n][j] = 0.f;

    const int r16 = lane & 15;
    const int kq = (lane >> 4) * 8;

    for (int k0 = 0; k0 < Ksp; k0 += BK) {
        // stage A,B tiles: 4 waves x 4 instrs x 1KB each per tile
#pragma unroll
        for (int i = 0; i < 4; ++i) {
            const int rr = (w * 4 + i) * 8;   // 8-row chunk base (wave-uniform)
            gload16(gA + (long)rr * lda + k0, (void*)&As[rr * BK]);
            gload16(gB + (long)rr * ldb + k0, (void*)&Bs[rr * BK]);
        }
        __syncthreads();   // compiler drains vmcnt(0) here

#pragma unroll
        for (int ks = 0; ks < 2; ++ks) {
            bf16x8 af[4], bv[4];
#pragma unroll
            for (int m = 0; m < 4; ++m)
                af[m] = *(const bf16x8*)&As[(wr * 64 + m * 16 + r16) * BK + ks * 32 + kq];
#pragma unroll
            for (int n = 0; n < 4; ++n)
                bv[n] = *(const bf16x8*)&Bs[(wc * 64 + n * 16 + r16) * BK + ks * 32 + kq];
#pragma unroll
            for (int m = 0; m < 4; ++m)
#pragma unroll
                for (int n = 0; n < 4; ++n)
                    acc[m][n] = __builtin_amdgcn_mfma_f32_16x16x32_bf16(af[m], bv[n], acc[m][n], 0, 0, 0);
        }
        __syncthreads();
    }

    const bool relu = (flags & 1) != 0;
#pragma unroll
    for (int m = 0; m < 4; ++m) {
        const int gr0 = tM + wr * 64 + m * 16 + (lane >> 4) * 4;
#pragma unroll
        for (int n = 0; n < 4; ++n) {
            const int gc = tN + wc * 64 + n * 16 + (lane & 15);
            const float bb = bias ? bias[gc] : 0.f;
#pragma unroll
            for (int j = 0; j < 4; ++j) {
                float v = acc[m][n][j] + bb;
                if (relu) v = fmaxf(v, 0.f);
                const long idx = cbase + (long)(gr0 + j) * ldc + gc;
                if (Cb) Cb[idx] = (__bf16)v;
                else Cf[idx] = v;
            }
        }
    }
}

// ---------------------------------------------------------------------------
// LayerNorm over D=1024, one block/row, bf16 out.
// ---------------------------------------------------------------------------
__global__ __launch_bounds__(256) void ln_bf16(
    const float* __restrict__ x, const float* __restrict__ g,
    const float* __restrict__ bb, __bf16* __restrict__ out)
{
    const long row = blockIdx.x;
    const float* xr = x + row * ND;
    __bf16* orow = out + row * ND;
    const int t = threadIdx.x;
    float4 v = reinterpret_cast<const float4*>(xr)[t];
    float s = v.x + v.y + v.z + v.w;
    float s2 = v.x * v.x + v.y * v.y + v.z * v.z + v.w * v.w;
#pragma unroll
    for (int o = 32; o > 0; o >>= 1) {
        s += __shfl_xor(s, o, 64);
        s2 += __shfl_xor(s2, o, 64);
    }
    __shared__ float red[8];
    const int lane = t & 63, wv = t >> 6;
    if (lane == 0) { red[wv] = s; red[4 + wv] = s2; }
    __syncthreads();
    s = red[0] + red[1] + red[2] + red[3];
    s2 = red[4] + red[5] + red[6] + red[7];
    const float mean = s * (1.f / ND);
    const float var = s2 * (1.f / ND) - mean * mean;
    const float rs = rsqrtf(var + 1e-5f);
    const float xv[4] = {v.x, v.y, v.z, v.w};
#pragma unroll
    for (int j = 0; j < 4; ++j) {
        const int c = t * 4 + j;
        orow[c] = (__bf16)((xv[j] - mean) * rs * g[c] + bb[c]);
    }
}

// fp32 [rows_in, cols_in] -> bf16 [cols_in, ldo] transpose (zero-pad k >= rows_in)
__global__ void transpose_conv(const float* __restrict__ in, __bf16* __restrict__ out,
                               int rows_in, int cols_in, int ldo)
{
    __shared__ float tile[32][33];
    const int k0 = blockIdx.x * 32;
    const int n0 = blockIdx.y * 32;
    const int tx = threadIdx.x, ty = threadIdx.y;
#pragma unroll
    for (int dy = 0; dy < 32; dy += 8) {
        const int k = k0 + ty + dy, n = n0 + tx;
        tile[ty + dy][tx] = (k < rows_in && n < cols_in) ? in[(long)k * cols_in + n] : 0.f;
    }
    __syncthreads();
#pragma unroll
    for (int dy = 0; dy < 32; dy += 8) {
        const int n = n0 + ty + dy, k = k0 + tx;
        if (n < cols_in && k < ldo) out[(long)n * ldo + k] = (__bf16)tile[tx][ty + dy];
    }
}

// rel_k_emb [R,128] fp32 -> [128,128] bf16 zero-padded rows
__global__ void convert_pad_relk(const float* __restrict__ in, __bf16* __restrict__ out, int R)
{
    const int idx = blockIdx.x * 256 + threadIdx.x;
    if (idx >= 128 * NDK) return;
    const int r = idx / NDK;
    out[idx] = (r < R) ? (__bf16)in[idx] : (__bf16)0.f;
}

__global__ void pack_bias(const float* __restrict__ bq, const float* __restrict__ bk,
                          const float* __restrict__ bv, float* __restrict__ out,
                          float* __restrict__ loss_ws)
{
    const int t = blockIdx.x * 256 + threadIdx.x;
    if (t == 0) loss_ws[0] = 0.f;
    if (t < ND) out[t] = bq[t];
    else if (t < 2 * ND) out[t] = bk[t - ND];
    else if (t < 3 * ND) out[t] = bv[t - 2 * ND];
}

// V slice of packed qkvb [1024,3072] -> vt [B,H,DK,S] bf16
__global__ void transpose_v(const __bf16* __restrict__ qkvb, __bf16* __restrict__ vt)
{
    __shared__ __bf16 tile[32][33];
    const int bh = blockIdx.z, b = bh >> 3, h = bh & 7;
    const int d0 = blockIdx.x * 32, i0 = blockIdx.y * 32;
    const int tx = threadIdx.x, ty = threadIdx.y;
    const __bf16* src = qkvb + 2 * ND + h * NDK;
#pragma unroll
    for (int dy = 0; dy < 32; dy += 8)
        tile[ty + dy][tx] = src[(long)(b * NS + i0 + ty + dy) * (3 * ND) + d0 + tx];
    __syncthreads();
#pragma unroll
    for (int dy = 0; dy < 32; dy += 8)
        vt[((long)bh * NDK + d0 + ty + dy) * NS + i0 + tx] = tile[tx][ty + dy];
}

// ---------------------------------------------------------------------------
// Fused softmax + relation gather + attnR binning + history-loss partial.
// ---------------------------------------------------------------------------
__global__ __launch_bounds__(256) void softmax_rel(
    const float* __restrict__ scores, const float* __restrict__ qr,
    const int* __restrict__ relation, const int* __restrict__ mask,
    __bf16* __restrict__ attn, __bf16* __restrict__ attnR,
    float* __restrict__ loss_acc, const int* __restrict__ sep_p)
{
    const int i = blockIdx.x, h = blockIdx.y, b = blockIdx.z;
    const long bh = (long)(b * NH + h);
    const float* srow = scores + (bh * NS + i) * NS;
    const float* qrow = qr + (bh * NS + i) * QRLD;
    const int* rrow = relation + ((long)b * NS + i) * NS;
    const int* mrow = mask + ((long)b * NS + i) * NS;
    __bf16* arow = attn + (bh * NS + i) * NS;
    __bf16* aRrow = attnR + (bh * NS + i) * RPAD;

    __shared__ float qrl[RPAD];
    __shared__ float bins[RPAD];
    __shared__ float red[4];

    const int t = threadIdx.x;
    if (t < RPAD) { qrl[t] = qrow[t]; bins[t] = 0.f; }
    __syncthreads();

    const float sc = 0.088388347648318447f;  // 1/sqrt(128)
    const int r0 = rrow[t], r1 = rrow[t + 256];
    float v0 = (srow[t] + qrl[r0]) * sc;
    float v1 = (srow[t + 256] + qrl[r1]) * sc;
    if (mrow[t] == 0) v0 = -1e9f;
    if (mrow[t + 256] == 0) v1 = -1e9f;

    const int lane = t & 63, wv = t >> 6;

    float mx = fmaxf(v0, v1);
#pragma unroll
    for (int o = 32; o > 0; o >>= 1) mx = fmaxf(mx, __shfl_xor(mx, o, 64));
    if (lane == 0) red[wv] = mx;
    __syncthreads();
    mx = fmaxf(fmaxf(red[0], red[1]), fmaxf(red[2], red[3]));
    __syncthreads();

    const float e0 = __expf(v0 - mx), e1 = __expf(v1 - mx);
    float sm = e0 + e1;
#pragma unroll
    for (int o = 32; o > 0; o >>= 1) sm += __shfl_xor(sm, o, 64);
    if (lane == 0) red[wv] = sm;
    __syncthreads();
    sm = red[0] + red[1] + red[2] + red[3];
    __syncthreads();

    const float inv = 1.f / sm;
    const float a0 = e0 * inv, a1 = e1 * inv;
    arow[t] = (__bf16)a0;
    arow[t + 256] = (__bf16)a1;
    atomicAdd(&bins[r0], a0);
    atomicAdd(&bins[r1], a1);

    const int sep = *sep_p;
    float ls = 0.f;
    if (t < sep) ls += a0;
    if (t + 256 < sep) ls += a1;
#pragma unroll
    for (int o = 32; o > 0; o >>= 1) ls += __shfl_xor(ls, o, 64);
    if (lane == 0) red[wv] = ls;
    __syncthreads();  // also fences bins atomics
    if (t == 0) atomicAdd(loss_acc, red[0] + red[1] + red[2] + red[3]);
    if (t < RPAD) aRrow[t] = (__bf16)bins[t];
}

// ctx split-K reduce + fused attnR@rel_v + merge_heads -> ctxm bf16 [B*S, D]
__global__ __launch_bounds__(256) void ctx_reduce(
    const float* __restrict__ P, const __bf16* __restrict__ attnR,
    const __bf16* __restrict__ relvT, __bf16* __restrict__ ctxm)
{
    const int idx = blockIdx.x * 256 + threadIdx.x;  // bh*65536 + i*128 + d
    const int d = idx & 127;
    const int i = (idx >> 7) & 511;
    const int h = (idx >> 16) & 7;
    const int b = idx >> 19;
    const long sP = (long)NBH * NS * NDK;
    float s = P[idx] + P[idx + sP] + P[idx + 2 * sP] + P[idx + 3 * sP];

    const bf16x8* ar = (const bf16x8*)(attnR + ((long)(idx >> 16) * NS + i) * RPAD);
    const bf16x8* rv = (const bf16x8*)(relvT + (long)d * RPAD);
    float acc = 0.f;
#pragma unroll
    for (int q = 0; q < 8; ++q) {
        bf16x8 a = ar[q], vv = rv[q];
#pragma unroll
        for (int j = 0; j < 8; ++j) acc += (float)a[j] * (float)vv[j];
    }
    ctxm[((long)(b * NS + i)) * ND + h * NDK + d] = (__bf16)(s + acc);
}

// Wo split-K reduce: out = x + bo + sum_4 partials
__global__ __launch_bounds__(256) void wo_reduce(
    const float* __restrict__ P, const float* __restrict__ x,
    const float* __restrict__ bo, float* __restrict__ out)
{
    const int i4 = blockIdx.x * 256 + threadIdx.x;  // 262144 float4s
    const long sP = (long)BSROWS * ND / 4;
    const float4* P4 = (const float4*)P;
    float4 s = P4[i4];
    const float4 t1 = P4[i4 + sP], t2 = P4[i4 + 2 * sP], t3 = P4[i4 + 3 * sP];
    s.x += t1.x + t2.x + t3.x; s.y += t1.y + t2.y + t3.y;
    s.z += t1.z + t2.z + t3.z; s.w += t1.w + t2.w + t3.w;
    const int col = (i4 * 4) & (ND - 1);
    const float4 xv = ((const float4*)x)[i4];
    const float4 bv = *(const float4*)&bo[col];
    float4 o;
    o.x = s.x + xv.x + bv.x; o.y = s.y + xv.y + bv.y;
    o.z = s.z + xv.z + bv.z; o.w = s.w + xv.w + bv.w;
    ((float4*)out)[i4] = o;
}

// FFN2 split-K reduce: out += b2 + sum_8 partials
__global__ __launch_bounds__(256) void ffn2_reduce(
    const float* __restrict__ P, const float* __restrict__ b2, float* __restrict__ out)
{
    const int i4 = blockIdx.x * 256 + threadIdx.x;
    const long sP = (long)BSROWS * ND / 4;
    const float4* P4 = (const float4*)P;
    float4 s = P4[i4];
#pragma unroll
    for (int sp = 1; sp < 8; ++sp) {
        const float4 t = P4[i4 + sp * sP];
        s.x += t.x; s.y += t.y; s.z += t.z; s.w += t.w;
    }
    const int col = (i4 * 4) & (ND - 1);
    const float4 bv = *(const float4*)&b2[col];
    float4 o = ((float4*)out)[i4];
    o.x += s.x + bv.x; o.y += s.y + bv.y;
    o.z += s.z + bv.z; o.w += s.w + bv.w;
    ((float4*)out)[i4] = o;
}

__global__ void finalize_loss(const float* __restrict__ loss_ws,
                              const float* __restrict__ hist,
                              const int* __restrict__ sep_p,
                              float* __restrict__ out_loss)
{
    const int sep = *sep_p;
    const float denom = (float)NB * NH * NS * (float)(sep > 0 ? sep : 1);
    out_loss[0] = (sep > 0) ? hist[0] * loss_ws[0] / denom : 0.f;
}

// ---------------------------------------------------------------------------
static inline int cdiv(int a, int b) { return (a + b - 1) / b; }

extern "C" void kernel_launch(void* const* d_in, const int* in_sizes, int n_in,
                              void* d_out, int out_size, void* d_ws, size_t ws_size,
                              hipStream_t stream)
{
    const float* x      = (const float*)d_in[0];
    const int* relation = (const int*)d_in[1];
    const int* mask     = (const int*)d_in[2];
    const int* sep_p    = (const int*)d_in[3];
    const float* hist   = (const float*)d_in[4];
    const float* Wq = (const float*)d_in[5],  *bq = (const float*)d_in[6];
    const float* Wk = (const float*)d_in[7],  *bk = (const float*)d_in[8];
    const float* Wv = (const float*)d_in[9],  *bv = (const float*)d_in[10];
    const float* Wo = (const float*)d_in[11], *bo = (const float*)d_in[12];
    const float* relk = (const float*)d_in[13];
    const float* relv = (const float*)d_in[14];
    const float* ln1g = (const float*)d_in[15], *ln1b = (const float*)d_in[16];
    const float* ln2g = (const float*)d_in[17], *ln2b = (const float*)d_in[18];
    const float* W1 = (const float*)d_in[19], *b1 = (const float*)d_in[20];
    const float* W2 = (const float*)d_in[21], *b2 = (const float*)d_in[22];
    const int R = in_sizes[13] / NDK;  // 51

    float* out = (float*)d_out;
    float* out_loss = out + (long)BSROWS * ND;

    char* p = (char*)d_ws;
    auto alloc = [&](size_t bytes) -> void* {
        void* r = (void*)p;
        p += (bytes + 255) & ~(size_t)255;
        return r;
    };
    __bf16* WqkvT   = (__bf16*)alloc((size_t)3 * ND * ND * 2);
    __bf16* WoT     = (__bf16*)alloc((size_t)ND * ND * 2);
    __bf16* W1T     = (__bf16*)alloc((size_t)NDFF * ND * 2);
    __bf16* W2T     = (__bf16*)alloc((size_t)ND * NDFF * 2);
    __bf16* relkT   = (__bf16*)alloc((size_t)128 * NDK * 2);
    __bf16* relvT   = (__bf16*)alloc((size_t)NDK * RPAD * 2);
    float*  biasqkv = (float*)alloc((size_t)3 * ND * 4);
    __bf16* h1      = (__bf16*)alloc((size_t)BSROWS * ND * 2);
    __bf16* qkvb    = (__bf16*)alloc((size_t)BSROWS * 3 * ND * 2);
    __bf16* vt      = (__bf16*)alloc((size_t)NBH * NDK * NS * 2);
    float*  qr      = (float*)alloc((size_t)NBH * NS * QRLD * 4);
    __bf16* attnb   = (__bf16*)alloc((size_t)NBH * NS * NS * 2);
    __bf16* attnR   = (__bf16*)alloc((size_t)NBH * NS * RPAD * 2);
    __bf16* ctxm    = (__bf16*)alloc((size_t)BSROWS * ND * 2);
    __bf16* h2      = (__bf16*)alloc((size_t)BSROWS * ND * 2);
    __bf16* F1      = (__bf16*)alloc((size_t)BSROWS * NDFF * 2);
    float*  loss_ws = (float*)alloc(256);
    float*  arena   = (float*)alloc((size_t)32 * 1024 * 1024);
    // arena aliasing (lifetimes disjoint):
    float* scoresb = arena;                          // 16 MB, dead after softmax
    float* ctxPart = arena + (size_t)4 * 1024 * 1024;// 16 MB, dead after ctx_reduce
    float* woPart  = arena;                          // 16 MB, dead after wo_reduce
    float* f2Part  = arena;                          // 32 MB

    const dim3 tb(32, 8);
    transpose_conv<<<dim3(32, 32), tb, 0, stream>>>(Wq, WqkvT, ND, ND, ND);
    transpose_conv<<<dim3(32, 32), tb, 0, stream>>>(Wk, WqkvT + (size_t)ND * ND, ND, ND, ND);
    transpose_conv<<<dim3(32, 32), tb, 0, stream>>>(Wv, WqkvT + (size_t)2 * ND * ND, ND, ND, ND);
    transpose_conv<<<dim3(32, 32), tb, 0, stream>>>(Wo, WoT, ND, ND, ND);
    transpose_conv<<<dim3(32, 128), tb, 0, stream>>>(W1, W1T, ND, NDFF, ND);
    transpose_conv<<<dim3(128, 32), tb, 0, stream>>>(W2, W2T, NDFF, ND, NDFF);
    transpose_conv<<<dim3(2, 4), tb, 0, stream>>>(relv, relvT, R, NDK, RPAD);
    convert_pad_relk<<<64, 256, 0, stream>>>(relk, relkT, R);
    pack_bias<<<12, 256, 0, stream>>>(bq, bk, bv, biasqkv, loss_ws);

    ln_bf16<<<BSROWS, 256, 0, stream>>>(x, ln1g, ln1b, h1);

    // QKV: [1024,1024] @ [3072,1024]^T -> qkvb bf16 [1024,3072]
    gemm128<<<dim3(24, 8, 1), 256, 0, stream>>>(
        h1, WqkvT, nullptr, qkvb, biasqkv,
        ND, ND, ND, 3 * ND,
        0, 0, 1, 0, 0, 1, 0, 1, 0, 0);

    transpose_v<<<dim3(4, 16, NBH), tb, 0, stream>>>(qkvb, vt);

    // qr[bh,i,r] = q . rel_k : per-head A = qkvb col-slice, K=128
    gemm128<<<dim3(1, 4, NBH), 256, 0, stream>>>(
        qkvb, relkT, qr, nullptr, nullptr,
        NDK, 3 * ND, NDK, QRLD,
        (long)NS * 3 * ND, NDK, NH,
        0, 0, 1,
        (long)NS * QRLD, 1, 0, 0);

    // scores = q @ k^T (per-head col-slices of qkvb)
    gemm128<<<dim3(4, 4, NBH), 256, 0, stream>>>(
        qkvb, qkvb + ND, scoresb, nullptr, nullptr,
        NDK, 3 * ND, 3 * ND, NS,
        (long)NS * 3 * ND, NDK, NH,
        (long)NS * 3 * ND, NDK, NH,
        (long)NS * NS, 1, 0, 0);

    softmax_rel<<<dim3(NS, NH, NB), 256, 0, stream>>>(
        scoresb, qr, relation, mask, attnb, attnR, loss_ws, sep_p);

    // ctx = attn @ v : split-K x4 (Ksp=128), batch 16
    gemm128<<<dim3(1, 4, NBH * 4), 256, 0, stream>>>(
        attnb, vt, ctxPart, nullptr, nullptr,
        128, NS, NS, NDK,
        (long)NS * NS, 0, 1,
        (long)NDK * NS, 0, 1,
        (long)NS * NDK, 4, (long)NBH * NS * NDK, 0);

    ctx_reduce<<<4096, 256, 0, stream>>>(ctxPart, attnR, relvT, ctxm);

    // attn_out partials: ctxm @ Wo, split-K x4 (Ksp=256)
    gemm128<<<dim3(8, 8, 4), 256, 0, stream>>>(
        ctxm, WoT, woPart, nullptr, nullptr,
        256, ND, ND, ND,
        0, 0, 1, 0, 0, 1,
        0, 4, (long)BSROWS * ND, 0);

    wo_reduce<<<1024, 256, 0, stream>>>(woPart, x, bo, out);

    ln_bf16<<<BSROWS, 256, 0, stream>>>(out, ln2g, ln2b, h2);

    // FFN1: relu(h2 @ W1 + b1) -> F1 bf16 [1024,4096]
    gemm128<<<dim3(32, 8, 1), 256, 0, stream>>>(
        h2, W1T, nullptr, F1, b1,
        ND, ND, ND, NDFF,
        0, 0, 1, 0, 0, 1, 0, 1, 0, 1);

    // FFN2 partials: F1 @ W2, split-K x8 (Ksp=512)
    gemm128<<<dim3(8, 8, 8), 256, 0, stream>>>(
        F1, W2T, f2Part, nullptr, nullptr,
        512, NDFF, NDFF, ND,
        0, 0, 1, 0, 0, 1,
        0, 8, (long)BSROWS * ND, 0);

    ffn2_reduce<<<1024, 256, 0, stream>>>(f2Part, b2, out);

    finalize_loss<<<1, 1, 0, stream>>>(loss_ws, hist, sep_p, out_loss);
}

// Round 3
// 235.950 us; speedup vs baseline: 2.5385x; 1.3224x over previous
//
#include <hip/hip_runtime.h>
#include <hip/hip_bf16.h>

#define NB 2
#define NS 512
#define ND 1024
#define NH 8
#define NDK 128
#define NDFF 4096
#define QRLD 128
#define RPAD 64
#define BSROWS 1024           /* B*S */
#define NBH 16                /* B*H */

typedef __bf16 bf16x8 __attribute__((ext_vector_type(8)));
typedef float f32x4 __attribute__((ext_vector_type(4)));

#define BM 128
#define BN 128
#define BK 64

__device__ __forceinline__ void gload16(const void* g, void* l) {
    __builtin_amdgcn_global_load_lds(
        (const __attribute__((address_space(1))) void*)g,
        (__attribute__((address_space(3))) void*)l, 16, 0, 0);
}

// ---------------------------------------------------------------------------
// m97-structure GEMM: C[M,N] = A[M,K] @ Bt[N,K]^T. 128x128 tile, BK=64,
// 4 waves (each 64x64 via 4x4 16x16x32 MFMA), global_load_lds staging.
// Batch via z: bh = z/nsplit, sp = z%nsplit; K-window = [sp*Ksp, (sp+1)*Ksp).
// ---------------------------------------------------------------------------
__global__ __launch_bounds__(256) void gemm128(
    const __bf16* __restrict__ A, const __bf16* __restrict__ Bt,
    float* __restrict__ Cf, __bf16* __restrict__ Cb,
    const float* __restrict__ bias,
    int Ksp, int lda, int ldb, int ldc,
    long sA, long sA2, int zdivA,
    long sB, long sB2, int zdivB,
    long sC, int nsplit, long sPart, int flags)
{
    __shared__ __bf16 As[BM * BK];
    __shared__ __bf16 Bs[BN * BK];

    const int z = blockIdx.z;
    const int bh = z / nsplit, sp = z - bh * nsplit;
    const long kbase = (long)sp * Ksp;
    A  += (long)(bh / zdivA) * sA + (long)(bh % zdivA) * sA2 + kbase;
    Bt += (long)(bh / zdivB) * sB + (long)(bh % zdivB) * sB2 + kbase;
    const long cbase = (long)bh * sC + (long)sp * sPart;

    const int tM = blockIdx.y * BM, tN = blockIdx.x * BN;
    const int t = threadIdx.x, lane = t & 63, w = t >> 6;
    const int wr = w >> 1, wc = w & 1;
    const int srow = lane >> 3;          // 0..7 within 8-row chunk
    const int scol = (lane & 7) * 8;     // element col within BK

    const __bf16* gA = A + (long)(tM + srow) * lda + scol;
    const __bf16* gB = Bt + (long)(tN + srow) * ldb + scol;

    f32x4 acc[4][4];
#pragma unroll
    for (int m = 0; m < 4; ++m)
#pragma unroll
        for (int n = 0; n < 4; ++n)
#pragma unroll
            for (int j = 0; j < 4; ++j) acc[m][n][j] = 0.f;

    const int r16 = lane & 15;
    const int kq = (lane >> 4) * 8;

    for (int k0 = 0; k0 < Ksp; k0 += BK) {
#pragma unroll
        for (int i = 0; i < 4; ++i) {
            const int rr = (w * 4 + i) * 8;   // 8-row chunk base (wave-uniform)
            gload16(gA + (long)rr * lda + k0, (void*)&As[rr * BK]);
            gload16(gB + (long)rr * ldb + k0, (void*)&Bs[rr * BK]);
        }
        __syncthreads();

#pragma unroll
        for (int ks = 0; ks < 2; ++ks) {
            bf16x8 af[4], bv[4];
#pragma unroll
            for (int m = 0; m < 4; ++m)
                af[m] = *(const bf16x8*)&As[(wr * 64 + m * 16 + r16) * BK + ks * 32 + kq];
#pragma unroll
            for (int n = 0; n < 4; ++n)
                bv[n] = *(const bf16x8*)&Bs[(wc * 64 + n * 16 + r16) * BK + ks * 32 + kq];
#pragma unroll
            for (int m = 0; m < 4; ++m)
#pragma unroll
                for (int n = 0; n < 4; ++n)
                    acc[m][n] = __builtin_amdgcn_mfma_f32_16x16x32_bf16(af[m], bv[n], acc[m][n], 0, 0, 0);
        }
        __syncthreads();
    }

    const bool relu = (flags & 1) != 0;
#pragma unroll
    for (int m = 0; m < 4; ++m) {
        const int gr0 = tM + wr * 64 + m * 16 + (lane >> 4) * 4;
#pragma unroll
        for (int n = 0; n < 4; ++n) {
            const int gc = tN + wc * 64 + n * 16 + (lane & 15);
            const float bb = bias ? bias[gc] : 0.f;
#pragma unroll
            for (int j = 0; j < 4; ++j) {
                float v = acc[m][n][j] + bb;
                if (relu) v = fmaxf(v, 0.f);
                const long idx = cbase + (long)(gr0 + j) * ldc + gc;
                if (Cb) Cb[idx] = (__bf16)v;
                else Cf[idx] = v;
            }
        }
    }
}

// ---------------------------------------------------------------------------
// LayerNorm over D=1024, one block/row, bf16 out.
// ---------------------------------------------------------------------------
__global__ __launch_bounds__(256) void ln_bf16(
    const float* __restrict__ x, const float* __restrict__ g,
    const float* __restrict__ bb, __bf16* __restrict__ out)
{
    const long row = blockIdx.x;
    const float* xr = x + row * ND;
    __bf16* orow = out + row * ND;
    const int t = threadIdx.x;
    float4 v = reinterpret_cast<const float4*>(xr)[t];
    float s = v.x + v.y + v.z + v.w;
    float s2 = v.x * v.x + v.y * v.y + v.z * v.z + v.w * v.w;
#pragma unroll
    for (int o = 32; o > 0; o >>= 1) {
        s += __shfl_xor(s, o, 64);
        s2 += __shfl_xor(s2, o, 64);
    }
    __shared__ float red[8];
    const int lane = t & 63, wv = t >> 6;
    if (lane == 0) { red[wv] = s; red[4 + wv] = s2; }
    __syncthreads();
    s = red[0] + red[1] + red[2] + red[3];
    s2 = red[4] + red[5] + red[6] + red[7];
    const float mean = s * (1.f / ND);
    const float var = s2 * (1.f / ND) - mean * mean;
    const float rs = rsqrtf(var + 1e-5f);
    const float xv[4] = {v.x, v.y, v.z, v.w};
#pragma unroll
    for (int j = 0; j < 4; ++j) {
        const int c = t * 4 + j;
        orow[c] = (__bf16)((xv[j] - mean) * rs * g[c] + bb[c]);
    }
}

// fp32 [rows_in, cols_in] -> bf16 [cols_in, ldo] transpose (zero-pad k >= rows_in)
__global__ void transpose_conv(const float* __restrict__ in, __bf16* __restrict__ out,
                               int rows_in, int cols_in, int ldo)
{
    __shared__ float tile[32][33];
    const int k0 = blockIdx.x * 32;
    const int n0 = blockIdx.y * 32;
    const int tx = threadIdx.x, ty = threadIdx.y;
#pragma unroll
    for (int dy = 0; dy < 32; dy += 8) {
        const int k = k0 + ty + dy, n = n0 + tx;
        tile[ty + dy][tx] = (k < rows_in && n < cols_in) ? in[(long)k * cols_in + n] : 0.f;
    }
    __syncthreads();
#pragma unroll
    for (int dy = 0; dy < 32; dy += 8) {
        const int n = n0 + ty + dy, k = k0 + tx;
        if (n < cols_in && k < ldo) out[(long)n * ldo + k] = (__bf16)tile[tx][ty + dy];
    }
}

// rel_k_emb [R,128] fp32 -> [128,128] bf16 zero-padded rows
__global__ void convert_pad_relk(const float* __restrict__ in, __bf16* __restrict__ out, int R)
{
    const int idx = blockIdx.x * 256 + threadIdx.x;
    if (idx >= 128 * NDK) return;
    const int r = idx / NDK;
    out[idx] = (r < R) ? (__bf16)in[idx] : (__bf16)0.f;
}

__global__ void pack_bias(const float* __restrict__ bq, const float* __restrict__ bk,
                          const float* __restrict__ bv, float* __restrict__ out)
{
    const int t = blockIdx.x * 256 + threadIdx.x;
    if (t < ND) out[t] = bq[t];
    else if (t < 2 * ND) out[t] = bk[t - ND];
    else if (t < 3 * ND) out[t] = bv[t - 2 * ND];
}

// V slice of packed qkvb [1024,3072] -> vt [B,H,DK,S] bf16
__global__ void transpose_v(const __bf16* __restrict__ qkvb, __bf16* __restrict__ vt)
{
    __shared__ __bf16 tile[32][33];
    const int bh = blockIdx.z, b = bh >> 3, h = bh & 7;
    const int d0 = blockIdx.x * 32, i0 = blockIdx.y * 32;
    const int tx = threadIdx.x, ty = threadIdx.y;
    const __bf16* src = qkvb + 2 * ND + h * NDK;
#pragma unroll
    for (int dy = 0; dy < 32; dy += 8)
        tile[ty + dy][tx] = src[(long)(b * NS + i0 + ty + dy) * (3 * ND) + d0 + tx];
    __syncthreads();
#pragma unroll
    for (int dy = 0; dy < 32; dy += 8)
        vt[((long)bh * NDK + d0 + ty + dy) * NS + i0 + tx] = tile[tx][ty + dy];
}

// ---------------------------------------------------------------------------
// Fused softmax + relation gather + attnR binning + history-loss partial.
// Loss partial goes to loss_part[bh*NS+i] (NO contended global atomic).
// ---------------------------------------------------------------------------
__global__ __launch_bounds__(256) void softmax_rel(
    const float* __restrict__ scores, const float* __restrict__ qr,
    const int* __restrict__ relation, const int* __restrict__ mask,
    __bf16* __restrict__ attn, __bf16* __restrict__ attnR,
    float* __restrict__ loss_part, const int* __restrict__ sep_p)
{
    const int i = blockIdx.x, h = blockIdx.y, b = blockIdx.z;
    const long bh = (long)(b * NH + h);
    const float* srow = scores + (bh * NS + i) * NS;
    const float* qrow = qr + (bh * NS + i) * QRLD;
    const int* rrow = relation + ((long)b * NS + i) * NS;
    const int* mrow = mask + ((long)b * NS + i) * NS;
    __bf16* arow = attn + (bh * NS + i) * NS;
    __bf16* aRrow = attnR + (bh * NS + i) * RPAD;

    __shared__ float qrl[RPAD];
    __shared__ float bins[RPAD];
    __shared__ float red[4];

    const int t = threadIdx.x;
    // issue global loads first (overlap latency with LDS fill)
    const float s0 = srow[t], s1 = srow[t + 256];
    const int r0 = rrow[t], r1 = rrow[t + 256];
    const int m0 = mrow[t], m1 = mrow[t + 256];
    if (t < RPAD) { qrl[t] = qrow[t]; bins[t] = 0.f; }
    __syncthreads();

    const float sc = 0.088388347648318447f;  // 1/sqrt(128)
    float v0 = (s0 + qrl[r0]) * sc;
    float v1 = (s1 + qrl[r1]) * sc;
    if (m0 == 0) v0 = -1e9f;
    if (m1 == 0) v1 = -1e9f;

    const int lane = t & 63, wv = t >> 6;

    float mx = fmaxf(v0, v1);
#pragma unroll
    for (int o = 32; o > 0; o >>= 1) mx = fmaxf(mx, __shfl_xor(mx, o, 64));
    if (lane == 0) red[wv] = mx;
    __syncthreads();
    mx = fmaxf(fmaxf(red[0], red[1]), fmaxf(red[2], red[3]));
    __syncthreads();

    const float e0 = __expf(v0 - mx), e1 = __expf(v1 - mx);
    float sm = e0 + e1;
#pragma unroll
    for (int o = 32; o > 0; o >>= 1) sm += __shfl_xor(sm, o, 64);
    if (lane == 0) red[wv] = sm;
    __syncthreads();
    sm = red[0] + red[1] + red[2] + red[3];
    __syncthreads();

    const float inv = 1.f / sm;
    const float a0 = e0 * inv, a1 = e1 * inv;
    arow[t] = (__bf16)a0;
    arow[t + 256] = (__bf16)a1;
    atomicAdd(&bins[r0], a0);
    atomicAdd(&bins[r1], a1);

    const int sep = *sep_p;
    float ls = 0.f;
    if (t < sep) ls += a0;
    if (t + 256 < sep) ls += a1;
#pragma unroll
    for (int o = 32; o > 0; o >>= 1) ls += __shfl_xor(ls, o, 64);
    if (lane == 0) red[wv] = ls;
    __syncthreads();  // also fences bins atomics
    if (t == 0) loss_part[bh * NS + i] = red[0] + red[1] + red[2] + red[3];
    if (t < RPAD) aRrow[t] = (__bf16)bins[t];
}

// ctx split-K reduce + fused attnR@rel_v + merge_heads -> ctxm bf16 [B*S, D]
__global__ __launch_bounds__(256) void ctx_reduce(
    const float* __restrict__ P, const __bf16* __restrict__ attnR,
    const __bf16* __restrict__ relvT, __bf16* __restrict__ ctxm)
{
    const int idx = blockIdx.x * 256 + threadIdx.x;  // bh*65536 + i*128 + d
    const int d = idx & 127;
    const int i = (idx >> 7) & 511;
    const int h = (idx >> 16) & 7;
    const int b = idx >> 19;
    const long sP = (long)NBH * NS * NDK;
    float s = P[idx] + P[idx + sP] + P[idx + 2 * sP] + P[idx + 3 * sP];

    const bf16x8* ar = (const bf16x8*)(attnR + ((long)(idx >> 16) * NS + i) * RPAD);
    const bf16x8* rv = (const bf16x8*)(relvT + (long)d * RPAD);
    float acc = 0.f;
#pragma unroll
    for (int q = 0; q < 8; ++q) {
        bf16x8 a = ar[q], vv = rv[q];
#pragma unroll
        for (int j = 0; j < 8; ++j) acc += (float)a[j] * (float)vv[j];
    }
    ctxm[((long)(b * NS + i)) * ND + h * NDK + d] = (__bf16)(s + acc);
}

// Wo split-K reduce: out = x + bo + sum_4 partials
__global__ __launch_bounds__(256) void wo_reduce(
    const float* __restrict__ P, const float* __restrict__ x,
    const float* __restrict__ bo, float* __restrict__ out)
{
    const int i4 = blockIdx.x * 256 + threadIdx.x;  // 262144 float4s
    const long sP = (long)BSROWS * ND / 4;
    const float4* P4 = (const float4*)P;
    float4 s = P4[i4];
    const float4 t1 = P4[i4 + sP], t2 = P4[i4 + 2 * sP], t3 = P4[i4 + 3 * sP];
    s.x += t1.x + t2.x + t3.x; s.y += t1.y + t2.y + t3.y;
    s.z += t1.z + t2.z + t3.z; s.w += t1.w + t2.w + t3.w;
    const int col = (i4 * 4) & (ND - 1);
    const float4 xv = ((const float4*)x)[i4];
    const float4 bv = *(const float4*)&bo[col];
    float4 o;
    o.x = s.x + xv.x + bv.x; o.y = s.y + xv.y + bv.y;
    o.z = s.z + xv.z + bv.z; o.w = s.w + xv.w + bv.w;
    ((float4*)out)[i4] = o;
}

// FFN2 split-K reduce: out += b2 + sum_8 partials
__global__ __launch_bounds__(256) void ffn2_reduce(
    const float* __restrict__ P, const float* __restrict__ b2, float* __restrict__ out)
{
    const int i4 = blockIdx.x * 256 + threadIdx.x;
    const long sP = (long)BSROWS * ND / 4;
    const float4* P4 = (const float4*)P;
    float4 s = P4[i4];
#pragma unroll
    for (int sp = 1; sp < 8; ++sp) {
        const float4 t = P4[i4 + sp * sP];
        s.x += t.x; s.y += t.y; s.z += t.z; s.w += t.w;
    }
    const int col = (i4 * 4) & (ND - 1);
    const float4 bv = *(const float4*)&b2[col];
    float4 o = ((float4*)out)[i4];
    o.x += s.x + bv.x; o.y += s.y + bv.y;
    o.z += s.z + bv.z; o.w += s.w + bv.w;
    ((float4*)out)[i4] = o;
}

// Reduce 8192 per-row loss partials in one block.
__global__ __launch_bounds__(256) void finalize_loss(
    const float* __restrict__ loss_part, const float* __restrict__ hist,
    const int* __restrict__ sep_p, float* __restrict__ out_loss)
{
    const int t = threadIdx.x;
    float s = 0.f;
#pragma unroll
    for (int k = 0; k < NBH * NS / 1024; ++k) {
        const float4 v = ((const float4*)loss_part)[t + k * 256];
        s += v.x + v.y + v.z + v.w;
    }
#pragma unroll
    for (int o = 32; o > 0; o >>= 1) s += __shfl_xor(s, o, 64);
    __shared__ float red[4];
    if ((t & 63) == 0) red[t >> 6] = s;
    __syncthreads();
    if (t == 0) {
        const int sep = *sep_p;
        const float total = red[0] + red[1] + red[2] + red[3];
        const float denom = (float)NB * NH * NS * (float)(sep > 0 ? sep : 1);
        out_loss[0] = (sep > 0) ? hist[0] * total / denom : 0.f;
    }
}

// ---------------------------------------------------------------------------
static inline int cdiv(int a, int b) { return (a + b - 1) / b; }

extern "C" void kernel_launch(void* const* d_in, const int* in_sizes, int n_in,
                              void* d_out, int out_size, void* d_ws, size_t ws_size,
                              hipStream_t stream)
{
    const float* x      = (const float*)d_in[0];
    const int* relation = (const int*)d_in[1];
    const int* mask     = (const int*)d_in[2];
    const int* sep_p    = (const int*)d_in[3];
    const float* hist   = (const float*)d_in[4];
    const float* Wq = (const float*)d_in[5],  *bq = (const float*)d_in[6];
    const float* Wk = (const float*)d_in[7],  *bk = (const float*)d_in[8];
    const float* Wv = (const float*)d_in[9],  *bv = (const float*)d_in[10];
    const float* Wo = (const float*)d_in[11], *bo = (const float*)d_in[12];
    const float* relk = (const float*)d_in[13];
    const float* relv = (const float*)d_in[14];
    const float* ln1g = (const float*)d_in[15], *ln1b = (const float*)d_in[16];
    const float* ln2g = (const float*)d_in[17], *ln2b = (const float*)d_in[18];
    const float* W1 = (const float*)d_in[19], *b1 = (const float*)d_in[20];
    const float* W2 = (const float*)d_in[21], *b2 = (const float*)d_in[22];
    const int R = in_sizes[13] / NDK;  // 51

    float* out = (float*)d_out;
    float* out_loss = out + (long)BSROWS * ND;

    char* p = (char*)d_ws;
    auto alloc = [&](size_t bytes) -> void* {
        void* r = (void*)p;
        p += (bytes + 255) & ~(size_t)255;
        return r;
    };
    __bf16* WqkvT   = (__bf16*)alloc((size_t)3 * ND * ND * 2);
    __bf16* WoT     = (__bf16*)alloc((size_t)ND * ND * 2);
    __bf16* W1T     = (__bf16*)alloc((size_t)NDFF * ND * 2);
    __bf16* W2T     = (__bf16*)alloc((size_t)ND * NDFF * 2);
    __bf16* relkT   = (__bf16*)alloc((size_t)128 * NDK * 2);
    __bf16* relvT   = (__bf16*)alloc((size_t)NDK * RPAD * 2);
    float*  biasqkv = (float*)alloc((size_t)3 * ND * 4);
    __bf16* h1      = (__bf16*)alloc((size_t)BSROWS * ND * 2);
    __bf16* qkvb    = (__bf16*)alloc((size_t)BSROWS * 3 * ND * 2);
    __bf16* vt      = (__bf16*)alloc((size_t)NBH * NDK * NS * 2);
    float*  qr      = (float*)alloc((size_t)NBH * NS * QRLD * 4);
    __bf16* attnb   = (__bf16*)alloc((size_t)NBH * NS * NS * 2);
    __bf16* attnR   = (__bf16*)alloc((size_t)NBH * NS * RPAD * 2);
    __bf16* ctxm    = (__bf16*)alloc((size_t)BSROWS * ND * 2);
    __bf16* h2      = (__bf16*)alloc((size_t)BSROWS * ND * 2);
    __bf16* F1      = (__bf16*)alloc((size_t)BSROWS * NDFF * 2);
    float*  loss_part = (float*)alloc((size_t)NBH * NS * 4);
    float*  arena   = (float*)alloc((size_t)32 * 1024 * 1024);
    // arena aliasing (lifetimes disjoint):
    float* scoresb = arena;                          // 16 MB, dead after softmax
    float* ctxPart = arena + (size_t)4 * 1024 * 1024;// 16 MB, dead after ctx_reduce
    float* woPart  = arena;                          // 16 MB, dead after wo_reduce
    float* f2Part  = arena;                          // 32 MB

    const dim3 tb(32, 8);
    transpose_conv<<<dim3(32, 32), tb, 0, stream>>>(Wq, WqkvT, ND, ND, ND);
    transpose_conv<<<dim3(32, 32), tb, 0, stream>>>(Wk, WqkvT + (size_t)ND * ND, ND, ND, ND);
    transpose_conv<<<dim3(32, 32), tb, 0, stream>>>(Wv, WqkvT + (size_t)2 * ND * ND, ND, ND, ND);
    transpose_conv<<<dim3(32, 32), tb, 0, stream>>>(Wo, WoT, ND, ND, ND);
    transpose_conv<<<dim3(32, 128), tb, 0, stream>>>(W1, W1T, ND, NDFF, ND);
    transpose_conv<<<dim3(128, 32), tb, 0, stream>>>(W2, W2T, NDFF, ND, NDFF);
    transpose_conv<<<dim3(2, 4), tb, 0, stream>>>(relv, relvT, R, NDK, RPAD);
    convert_pad_relk<<<64, 256, 0, stream>>>(relk, relkT, R);
    pack_bias<<<12, 256, 0, stream>>>(bq, bk, bv, biasqkv);

    ln_bf16<<<BSROWS, 256, 0, stream>>>(x, ln1g, ln1b, h1);

    // QKV: [1024,1024] @ [3072,1024]^T -> qkvb bf16 [1024,3072]
    gemm128<<<dim3(24, 8, 1), 256, 0, stream>>>(
        h1, WqkvT, nullptr, qkvb, biasqkv,
        ND, ND, ND, 3 * ND,
        0, 0, 1, 0, 0, 1, 0, 1, 0, 0);

    transpose_v<<<dim3(4, 16, NBH), tb, 0, stream>>>(qkvb, vt);

    // qr[bh,i,r] = q . rel_k : per-head A = qkvb col-slice, K=128
    gemm128<<<dim3(1, 4, NBH), 256, 0, stream>>>(
        qkvb, relkT, qr, nullptr, nullptr,
        NDK, 3 * ND, NDK, QRLD,
        (long)NS * 3 * ND, NDK, NH,
        0, 0, 1,
        (long)NS * QRLD, 1, 0, 0);

    // scores = q @ k^T (per-head col-slices of qkvb)
    gemm128<<<dim3(4, 4, NBH), 256, 0, stream>>>(
        qkvb, qkvb + ND, scoresb, nullptr, nullptr,
        NDK, 3 * ND, 3 * ND, NS,
        (long)NS * 3 * ND, NDK, NH,
        (long)NS * 3 * ND, NDK, NH,
        (long)NS * NS, 1, 0, 0);

    softmax_rel<<<dim3(NS, NH, NB), 256, 0, stream>>>(
        scoresb, qr, relation, mask, attnb, attnR, loss_part, sep_p);

    // ctx = attn @ v : split-K x4 (Ksp=128), batch 16
    gemm128<<<dim3(1, 4, NBH * 4), 256, 0, stream>>>(
        attnb, vt, ctxPart, nullptr, nullptr,
        128, NS, NS, NDK,
        (long)NS * NS, 0, 1,
        (long)NDK * NS, 0, 1,
        (long)NS * NDK, 4, (long)NBH * NS * NDK, 0);

    ctx_reduce<<<4096, 256, 0, stream>>>(ctxPart, attnR, relvT, ctxm);

    // attn_out partials: ctxm @ Wo, split-K x4 (Ksp=256)
    gemm128<<<dim3(8, 8, 4), 256, 0, stream>>>(
        ctxm, WoT, woPart, nullptr, nullptr,
        256, ND, ND, ND,
        0, 0, 1, 0, 0, 1,
        0, 4, (long)BSROWS * ND, 0);

    wo_reduce<<<1024, 256, 0, stream>>>(woPart, x, bo, out);

    ln_bf16<<<BSROWS, 256, 0, stream>>>(out, ln2g, ln2b, h2);

    // FFN1: relu(h2 @ W1 + b1) -> F1 bf16 [1024,4096]
    gemm128<<<dim3(32, 8, 1), 256, 0, stream>>>(
        h2, W1T, nullptr, F1, b1,
        ND, ND, ND, NDFF,
        0, 0, 1, 0, 0, 1, 0, 1, 0, 1);

    // FFN2 partials: F1 @ W2, split-K x8 (Ksp=512)
    gemm128<<<dim3(8, 8, 8), 256, 0, stream>>>(
        F1, W2T, f2Part, nullptr, nullptr,
        512, NDFF, NDFF, ND,
        0, 0, 1, 0, 0, 1,
        0, 8, (long)BSROWS * ND, 0);

    ffn2_reduce<<<1024, 256, 0, stream>>>(f2Part, b2, out);

    finalize_loss<<<1, 256, 0, stream>>>(loss_part, hist, sep_p, out_loss);
}

// Round 4
// 209.728 us; speedup vs baseline: 2.8559x; 1.1250x over previous
//
#include <hip/hip_runtime.h>
#include <hip/hip_bf16.h>

#define NB 2
#define NS 512
#define ND 1024
#define NH 8
#define NDK 128
#define NDFF 4096
#define QRLD 128
#define RPAD 64
#define BSROWS 1024           /* B*S */
#define NBH 16                /* B*H */

typedef __bf16 bf16x8 __attribute__((ext_vector_type(8)));
typedef float f32x4 __attribute__((ext_vector_type(4)));

#define BM 128
#define BN 128
#define BK 64

__device__ __forceinline__ void gload16(const void* g, void* l) {
    __builtin_amdgcn_global_load_lds(
        (const __attribute__((address_space(1))) void*)g,
        (__attribute__((address_space(3))) void*)l, 16, 0, 0);
}

// ---------------------------------------------------------------------------
// 2-phase double-buffered MFMA GEMM: C[M,N] = A[M,K] @ Bt[N,K]^T.
// 128x128 tile, BK=64, 4 waves. Static dbuf (As0/As1 distinct arrays) so the
// backend proves prefetch (global_load_lds -> buf^1) doesn't alias ds_reads
// of buf -> no serializing vmcnt between STAGE(next) and COMPUTE(cur).
// One __syncthreads per K-step (drains vmcnt AFTER compute overlapped it).
// Requires nt = Ksp/BK even and >= 2 (all call sites satisfy this).
// ---------------------------------------------------------------------------
__global__ __launch_bounds__(256) void gemm128(
    const __bf16* __restrict__ A, const __bf16* __restrict__ Bt,
    float* __restrict__ Cf, __bf16* __restrict__ Cb,
    const float* __restrict__ bias,
    int Ksp, int lda, int ldb, int ldc,
    long sA, long sA2, int zdivA,
    long sB, long sB2, int zdivB,
    long sC, int nsplit, long sPart, int flags)
{
    __shared__ __bf16 As0[BM * BK];
    __shared__ __bf16 As1[BM * BK];
    __shared__ __bf16 Bs0[BN * BK];
    __shared__ __bf16 Bs1[BN * BK];

    const int z = blockIdx.z;
    const int bh = z / nsplit, sp = z - bh * nsplit;
    const long kbase = (long)sp * Ksp;
    A  += (long)(bh / zdivA) * sA + (long)(bh % zdivA) * sA2 + kbase;
    Bt += (long)(bh / zdivB) * sB + (long)(bh % zdivB) * sB2 + kbase;
    const long cbase = (long)bh * sC + (long)sp * sPart;

    const int tM = blockIdx.y * BM, tN = blockIdx.x * BN;
    const int t = threadIdx.x, lane = t & 63, w = t >> 6;
    const int wr = w >> 1, wc = w & 1;
    const int srow = lane >> 3;          // 0..7 within 8-row chunk
    const int scol = (lane & 7) * 8;     // element col within BK

    const __bf16* gA = A + (long)(tM + srow) * lda + scol;
    const __bf16* gB = Bt + (long)(tN + srow) * ldb + scol;

    f32x4 acc[4][4];
#pragma unroll
    for (int m = 0; m < 4; ++m)
#pragma unroll
        for (int n = 0; n < 4; ++n)
#pragma unroll
            for (int j = 0; j < 4; ++j) acc[m][n][j] = 0.f;

    const int r16 = lane & 15;
    const int kq = (lane >> 4) * 8;
    const int nt = Ksp / BK;

    auto STAGE = [&](__bf16* as, __bf16* bs, int k0) {
#pragma unroll
        for (int i = 0; i < 4; ++i) {
            const int rr = (w * 4 + i) * 8;   // wave-uniform 8-row chunk base
            gload16(gA + (long)rr * lda + k0, (void*)&as[rr * BK]);
            gload16(gB + (long)rr * ldb + k0, (void*)&bs[rr * BK]);
        }
    };
    auto COMPUTE = [&](const __bf16* as, const __bf16* bs) {
#pragma unroll
        for (int ks = 0; ks < 2; ++ks) {
            bf16x8 af[4], bv[4];
#pragma unroll
            for (int m = 0; m < 4; ++m)
                af[m] = *(const bf16x8*)&as[(wr * 64 + m * 16 + r16) * BK + ks * 32 + kq];
#pragma unroll
            for (int n = 0; n < 4; ++n)
                bv[n] = *(const bf16x8*)&bs[(wc * 64 + n * 16 + r16) * BK + ks * 32 + kq];
#pragma unroll
            for (int m = 0; m < 4; ++m)
#pragma unroll
                for (int n = 0; n < 4; ++n)
                    acc[m][n] = __builtin_amdgcn_mfma_f32_16x16x32_bf16(af[m], bv[n], acc[m][n], 0, 0, 0);
        }
    };

    STAGE(As0, Bs0, 0);
    __syncthreads();                       // drains prologue vmcnt
    for (int tt = 0; tt < nt; tt += 2) {
        STAGE(As1, Bs1, (tt + 1) * BK);    // prefetch while computing buf0
        COMPUTE(As0, Bs0);
        __syncthreads();                   // vmcnt(0): buf1 ready; lgkm drained
        if (tt + 2 < nt) STAGE(As0, Bs0, (tt + 2) * BK);
        COMPUTE(As1, Bs1);
        __syncthreads();
    }

    const bool relu = (flags & 1) != 0;
#pragma unroll
    for (int m = 0; m < 4; ++m) {
        const int gr0 = tM + wr * 64 + m * 16 + (lane >> 4) * 4;
#pragma unroll
        for (int n = 0; n < 4; ++n) {
            const int gc = tN + wc * 64 + n * 16 + (lane & 15);
            const float bb = bias ? bias[gc] : 0.f;
#pragma unroll
            for (int j = 0; j < 4; ++j) {
                float v = acc[m][n][j] + bb;
                if (relu) v = fmaxf(v, 0.f);
                const long idx = cbase + (long)(gr0 + j) * ldc + gc;
                if (Cb) Cb[idx] = (__bf16)v;
                else Cf[idx] = v;
            }
        }
    }
}

// ---------------------------------------------------------------------------
// LayerNorm over D=1024, one block/row, bf16 out.
// ---------------------------------------------------------------------------
__global__ __launch_bounds__(256) void ln_bf16(
    const float* __restrict__ x, const float* __restrict__ g,
    const float* __restrict__ bb, __bf16* __restrict__ out)
{
    const long row = blockIdx.x;
    const float* xr = x + row * ND;
    __bf16* orow = out + row * ND;
    const int t = threadIdx.x;
    float4 v = reinterpret_cast<const float4*>(xr)[t];
    float s = v.x + v.y + v.z + v.w;
    float s2 = v.x * v.x + v.y * v.y + v.z * v.z + v.w * v.w;
#pragma unroll
    for (int o = 32; o > 0; o >>= 1) {
        s += __shfl_xor(s, o, 64);
        s2 += __shfl_xor(s2, o, 64);
    }
    __shared__ float red[8];
    const int lane = t & 63, wv = t >> 6;
    if (lane == 0) { red[wv] = s; red[4 + wv] = s2; }
    __syncthreads();
    s = red[0] + red[1] + red[2] + red[3];
    s2 = red[4] + red[5] + red[6] + red[7];
    const float mean = s * (1.f / ND);
    const float var = s2 * (1.f / ND) - mean * mean;
    const float rs = rsqrtf(var + 1e-5f);
    const float xv[4] = {v.x, v.y, v.z, v.w};
#pragma unroll
    for (int j = 0; j < 4; ++j) {
        const int c = t * 4 + j;
        orow[c] = (__bf16)((xv[j] - mean) * rs * g[c] + bb[c]);
    }
}

// ---------------------------------------------------------------------------
// Fused weight prep: all fp32->bf16 transposes in one launch.
// Block = (32,8); grid.x = 12296 range-decoded 32x32 tiles:
//   [0,4096)    : Wq/Wk/Wv -> WqkvT segments, Wo -> WoT   (32x32 tiles each)
//   [4096,8192) : W1 [1024,4096] -> W1T [4096,1024]
//   [8192,12288): W2 [4096,1024] -> W2T [1024,4096]
//   [12288,12296): relv [R,128] -> relvT [128,64] (zero-pad rows >= R)
// ---------------------------------------------------------------------------
__global__ void prep_weights(
    const float* __restrict__ Wq, const float* __restrict__ Wk,
    const float* __restrict__ Wv, const float* __restrict__ Wo,
    const float* __restrict__ W1, const float* __restrict__ W2,
    const float* __restrict__ relv,
    __bf16* __restrict__ WqkvT, __bf16* __restrict__ WoT,
    __bf16* __restrict__ W1T, __bf16* __restrict__ W2T,
    __bf16* __restrict__ relvT, int R)
{
    const int tile = blockIdx.x;
    const float* src; __bf16* dst;
    int rows_in, cols_in, ldo, kx, ny;
    if (tile < 4096) {
        const int m = tile >> 10, r = tile & 1023;
        kx = r & 31; ny = r >> 5;
        rows_in = 1024; cols_in = 1024; ldo = 1024;
        src = m == 0 ? Wq : m == 1 ? Wk : m == 2 ? Wv : Wo;
        dst = m == 3 ? WoT : WqkvT + (size_t)m * 1024 * 1024;
    } else if (tile < 8192) {
        const int r = tile - 4096;
        kx = r & 31; ny = r >> 5;
        rows_in = 1024; cols_in = 4096; ldo = 1024; src = W1; dst = W1T;
    } else if (tile < 12288) {
        const int r = tile - 8192;
        kx = r & 127; ny = r >> 7;
        rows_in = 4096; cols_in = 1024; ldo = 4096; src = W2; dst = W2T;
    } else {
        const int r = tile - 12288;
        kx = r & 1; ny = r >> 1;
        rows_in = R; cols_in = 128; ldo = 64; src = relv; dst = relvT;
    }

    __shared__ float tl[32][33];
    const int k0 = kx * 32, n0 = ny * 32;
    const int tx = threadIdx.x, ty = threadIdx.y;
#pragma unroll
    for (int dy = 0; dy < 32; dy += 8) {
        const int k = k0 + ty + dy, n = n0 + tx;
        tl[ty + dy][tx] = (k < rows_in && n < cols_in) ? src[(long)k * cols_in + n] : 0.f;
    }
    __syncthreads();
#pragma unroll
    for (int dy = 0; dy < 32; dy += 8) {
        const int n = n0 + ty + dy, k = k0 + tx;
        if (n < cols_in && k < ldo) dst[(long)n * ldo + k] = (__bf16)tl[tx][ty + dy];
    }
}

// pack_bias + relk pad in one launch (grid 76 x 256)
__global__ void prep_small(const float* __restrict__ bq, const float* __restrict__ bk,
                           const float* __restrict__ bv, const float* __restrict__ relk,
                           float* __restrict__ biasqkv, __bf16* __restrict__ relkT, int R)
{
    const int t = blockIdx.x * 256 + threadIdx.x;
    if (t < ND) biasqkv[t] = bq[t];
    else if (t < 2 * ND) biasqkv[t] = bk[t - ND];
    else if (t < 3 * ND) biasqkv[t] = bv[t - 2 * ND];
    else {
        const int idx = t - 3 * ND;
        if (idx < 128 * NDK) {
            const int r = idx / NDK;
            relkT[idx] = (r < R) ? (__bf16)relk[idx] : (__bf16)0.f;
        }
    }
}

// V slice of packed qkvb [1024,3072] -> vt [B,H,DK,S] bf16
__global__ void transpose_v(const __bf16* __restrict__ qkvb, __bf16* __restrict__ vt)
{
    __shared__ __bf16 tile[32][33];
    const int bh = blockIdx.z, b = bh >> 3, h = bh & 7;
    const int d0 = blockIdx.x * 32, i0 = blockIdx.y * 32;
    const int tx = threadIdx.x, ty = threadIdx.y;
    const __bf16* src = qkvb + 2 * ND + h * NDK;
#pragma unroll
    for (int dy = 0; dy < 32; dy += 8)
        tile[ty + dy][tx] = src[(long)(b * NS + i0 + ty + dy) * (3 * ND) + d0 + tx];
    __syncthreads();
#pragma unroll
    for (int dy = 0; dy < 32; dy += 8)
        vt[((long)bh * NDK + d0 + ty + dy) * NS + i0 + tx] = tile[tx][ty + dy];
}

// ---------------------------------------------------------------------------
// Fused softmax + relation gather + attnR binning + history-loss partial.
// Loss partial -> loss_part[bh*NS+i] (no contended global atomic).
// ---------------------------------------------------------------------------
__global__ __launch_bounds__(256) void softmax_rel(
    const float* __restrict__ scores, const float* __restrict__ qr,
    const int* __restrict__ relation, const int* __restrict__ mask,
    __bf16* __restrict__ attn, __bf16* __restrict__ attnR,
    float* __restrict__ loss_part, const int* __restrict__ sep_p)
{
    const int i = blockIdx.x, h = blockIdx.y, b = blockIdx.z;
    const long bh = (long)(b * NH + h);
    const float* srow = scores + (bh * NS + i) * NS;
    const float* qrow = qr + (bh * NS + i) * QRLD;
    const int* rrow = relation + ((long)b * NS + i) * NS;
    const int* mrow = mask + ((long)b * NS + i) * NS;
    __bf16* arow = attn + (bh * NS + i) * NS;
    __bf16* aRrow = attnR + (bh * NS + i) * RPAD;

    __shared__ float qrl[RPAD];
    __shared__ float bins[RPAD];
    __shared__ float red[4];

    const int t = threadIdx.x;
    const float s0 = srow[t], s1 = srow[t + 256];
    const int r0 = rrow[t], r1 = rrow[t + 256];
    const int m0 = mrow[t], m1 = mrow[t + 256];
    if (t < RPAD) { qrl[t] = qrow[t]; bins[t] = 0.f; }
    __syncthreads();

    const float sc = 0.088388347648318447f;  // 1/sqrt(128)
    float v0 = (s0 + qrl[r0]) * sc;
    float v1 = (s1 + qrl[r1]) * sc;
    if (m0 == 0) v0 = -1e9f;
    if (m1 == 0) v1 = -1e9f;

    const int lane = t & 63, wv = t >> 6;

    float mx = fmaxf(v0, v1);
#pragma unroll
    for (int o = 32; o > 0; o >>= 1) mx = fmaxf(mx, __shfl_xor(mx, o, 64));
    if (lane == 0) red[wv] = mx;
    __syncthreads();
    mx = fmaxf(fmaxf(red[0], red[1]), fmaxf(red[2], red[3]));
    __syncthreads();

    const float e0 = __expf(v0 - mx), e1 = __expf(v1 - mx);
    float sm = e0 + e1;
#pragma unroll
    for (int o = 32; o > 0; o >>= 1) sm += __shfl_xor(sm, o, 64);
    if (lane == 0) red[wv] = sm;
    __syncthreads();
    sm = red[0] + red[1] + red[2] + red[3];
    __syncthreads();

    const float inv = 1.f / sm;
    const float a0 = e0 * inv, a1 = e1 * inv;
    arow[t] = (__bf16)a0;
    arow[t + 256] = (__bf16)a1;
    atomicAdd(&bins[r0], a0);
    atomicAdd(&bins[r1], a1);

    const int sep = *sep_p;
    float ls = 0.f;
    if (t < sep) ls += a0;
    if (t + 256 < sep) ls += a1;
#pragma unroll
    for (int o = 32; o > 0; o >>= 1) ls += __shfl_xor(ls, o, 64);
    if (lane == 0) red[wv] = ls;
    __syncthreads();  // also fences bins atomics
    if (t == 0) loss_part[bh * NS + i] = red[0] + red[1] + red[2] + red[3];
    if (t < RPAD) aRrow[t] = (__bf16)bins[t];
}

// ctx split-K reduce + fused attnR@rel_v + merge_heads -> ctxm bf16 [B*S, D]
__global__ __launch_bounds__(256) void ctx_reduce(
    const float* __restrict__ P, const __bf16* __restrict__ attnR,
    const __bf16* __restrict__ relvT, __bf16* __restrict__ ctxm)
{
    const int idx = blockIdx.x * 256 + threadIdx.x;  // bh*65536 + i*128 + d
    const int d = idx & 127;
    const int i = (idx >> 7) & 511;
    const int h = (idx >> 16) & 7;
    const int b = idx >> 19;
    const long sP = (long)NBH * NS * NDK;
    float s = P[idx] + P[idx + sP] + P[idx + 2 * sP] + P[idx + 3 * sP];

    const bf16x8* ar = (const bf16x8*)(attnR + ((long)(idx >> 16) * NS + i) * RPAD);
    const bf16x8* rv = (const bf16x8*)(relvT + (long)d * RPAD);
    float acc = 0.f;
#pragma unroll
    for (int q = 0; q < 8; ++q) {
        bf16x8 a = ar[q], vv = rv[q];
#pragma unroll
        for (int j = 0; j < 8; ++j) acc += (float)a[j] * (float)vv[j];
    }
    ctxm[((long)(b * NS + i)) * ND + h * NDK + d] = (__bf16)(s + acc);
}

// Wo split-K reduce: out = x + bo + sum_4 partials
__global__ __launch_bounds__(256) void wo_reduce(
    const float* __restrict__ P, const float* __restrict__ x,
    const float* __restrict__ bo, float* __restrict__ out)
{
    const int i4 = blockIdx.x * 256 + threadIdx.x;
    const long sP = (long)BSROWS * ND / 4;
    const float4* P4 = (const float4*)P;
    float4 s = P4[i4];
    const float4 t1 = P4[i4 + sP], t2 = P4[i4 + 2 * sP], t3 = P4[i4 + 3 * sP];
    s.x += t1.x + t2.x + t3.x; s.y += t1.y + t2.y + t3.y;
    s.z += t1.z + t2.z + t3.z; s.w += t1.w + t2.w + t3.w;
    const int col = (i4 * 4) & (ND - 1);
    const float4 xv = ((const float4*)x)[i4];
    const float4 bv = *(const float4*)&bo[col];
    float4 o;
    o.x = s.x + xv.x + bv.x; o.y = s.y + xv.y + bv.y;
    o.z = s.z + xv.z + bv.z; o.w = s.w + xv.w + bv.w;
    ((float4*)out)[i4] = o;
}

// FFN2 split-K reduce: out += b2 + sum_8 partials
__global__ __launch_bounds__(256) void ffn2_reduce(
    const float* __restrict__ P, const float* __restrict__ b2, float* __restrict__ out)
{
    const int i4 = blockIdx.x * 256 + threadIdx.x;
    const long sP = (long)BSROWS * ND / 4;
    const float4* P4 = (const float4*)P;
    float4 s = P4[i4];
#pragma unroll
    for (int sp = 1; sp < 8; ++sp) {
        const float4 t = P4[i4 + sp * sP];
        s.x += t.x; s.y += t.y; s.z += t.z; s.w += t.w;
    }
    const int col = (i4 * 4) & (ND - 1);
    const float4 bv = *(const float4*)&b2[col];
    float4 o = ((float4*)out)[i4];
    o.x += s.x + bv.x; o.y += s.y + bv.y;
    o.z += s.z + bv.z; o.w += s.w + bv.w;
    ((float4*)out)[i4] = o;
}

// Reduce 8192 per-row loss partials in one block.
__global__ __launch_bounds__(256) void finalize_loss(
    const float* __restrict__ loss_part, const float* __restrict__ hist,
    const int* __restrict__ sep_p, float* __restrict__ out_loss)
{
    const int t = threadIdx.x;
    float s = 0.f;
#pragma unroll
    for (int k = 0; k < NBH * NS / 1024; ++k) {
        const float4 v = ((const float4*)loss_part)[t + k * 256];
        s += v.x + v.y + v.z + v.w;
    }
#pragma unroll
    for (int o = 32; o > 0; o >>= 1) s += __shfl_xor(s, o, 64);
    __shared__ float red[4];
    if ((t & 63) == 0) red[t >> 6] = s;
    __syncthreads();
    if (t == 0) {
        const int sep = *sep_p;
        const float total = red[0] + red[1] + red[2] + red[3];
        const float denom = (float)NB * NH * NS * (float)(sep > 0 ? sep : 1);
        out_loss[0] = (sep > 0) ? hist[0] * total / denom : 0.f;
    }
}

// ---------------------------------------------------------------------------
static inline int cdiv(int a, int b) { return (a + b - 1) / b; }

extern "C" void kernel_launch(void* const* d_in, const int* in_sizes, int n_in,
                              void* d_out, int out_size, void* d_ws, size_t ws_size,
                              hipStream_t stream)
{
    const float* x      = (const float*)d_in[0];
    const int* relation = (const int*)d_in[1];
    const int* mask     = (const int*)d_in[2];
    const int* sep_p    = (const int*)d_in[3];
    const float* hist   = (const float*)d_in[4];
    const float* Wq = (const float*)d_in[5],  *bq = (const float*)d_in[6];
    const float* Wk = (const float*)d_in[7],  *bk = (const float*)d_in[8];
    const float* Wv = (const float*)d_in[9],  *bv = (const float*)d_in[10];
    const float* Wo = (const float*)d_in[11], *bo = (const float*)d_in[12];
    const float* relk = (const float*)d_in[13];
    const float* relv = (const float*)d_in[14];
    const float* ln1g = (const float*)d_in[15], *ln1b = (const float*)d_in[16];
    const float* ln2g = (const float*)d_in[17], *ln2b = (const float*)d_in[18];
    const float* W1 = (const float*)d_in[19], *b1 = (const float*)d_in[20];
    const float* W2 = (const float*)d_in[21], *b2 = (const float*)d_in[22];
    const int R = in_sizes[13] / NDK;  // 51

    float* out = (float*)d_out;
    float* out_loss = out + (long)BSROWS * ND;

    char* p = (char*)d_ws;
    auto alloc = [&](size_t bytes) -> void* {
        void* r = (void*)p;
        p += (bytes + 255) & ~(size_t)255;
        return r;
    };
    __bf16* WqkvT   = (__bf16*)alloc((size_t)3 * ND * ND * 2);
    __bf16* WoT     = (__bf16*)alloc((size_t)ND * ND * 2);
    __bf16* W1T     = (__bf16*)alloc((size_t)NDFF * ND * 2);
    __bf16* W2T     = (__bf16*)alloc((size_t)ND * NDFF * 2);
    __bf16* relkT   = (__bf16*)alloc((size_t)128 * NDK * 2);
    __bf16* relvT   = (__bf16*)alloc((size_t)NDK * RPAD * 2);
    float*  biasqkv = (float*)alloc((size_t)3 * ND * 4);
    __bf16* h1      = (__bf16*)alloc((size_t)BSROWS * ND * 2);
    __bf16* qkvb    = (__bf16*)alloc((size_t)BSROWS * 3 * ND * 2);
    __bf16* vt      = (__bf16*)alloc((size_t)NBH * NDK * NS * 2);
    float*  qr      = (float*)alloc((size_t)NBH * NS * QRLD * 4);
    __bf16* attnb   = (__bf16*)alloc((size_t)NBH * NS * NS * 2);
    __bf16* attnR   = (__bf16*)alloc((size_t)NBH * NS * RPAD * 2);
    __bf16* ctxm    = (__bf16*)alloc((size_t)BSROWS * ND * 2);
    __bf16* h2      = (__bf16*)alloc((size_t)BSROWS * ND * 2);
    __bf16* F1      = (__bf16*)alloc((size_t)BSROWS * NDFF * 2);
    float*  loss_part = (float*)alloc((size_t)NBH * NS * 4);
    float*  arena   = (float*)alloc((size_t)32 * 1024 * 1024);
    // arena aliasing (lifetimes disjoint):
    float* scoresb = arena;                          // 16 MB, dead after softmax
    float* ctxPart = arena + (size_t)4 * 1024 * 1024;// 16 MB, dead after ctx_reduce
    float* woPart  = arena;                          // 16 MB, dead after wo_reduce
    float* f2Part  = arena;                          // 32 MB

    const dim3 tb(32, 8);
    prep_weights<<<12296, tb, 0, stream>>>(Wq, Wk, Wv, Wo, W1, W2, relv,
                                           WqkvT, WoT, W1T, W2T, relvT, R);
    prep_small<<<76, 256, 0, stream>>>(bq, bk, bv, relk, biasqkv, relkT, R);

    ln_bf16<<<BSROWS, 256, 0, stream>>>(x, ln1g, ln1b, h1);

    // QKV: [1024,1024] @ [3072,1024]^T -> qkvb bf16 [1024,3072]
    gemm128<<<dim3(24, 8, 1), 256, 0, stream>>>(
        h1, WqkvT, nullptr, qkvb, biasqkv,
        ND, ND, ND, 3 * ND,
        0, 0, 1, 0, 0, 1, 0, 1, 0, 0);

    transpose_v<<<dim3(4, 16, NBH), tb, 0, stream>>>(qkvb, vt);

    // qr[bh,i,r] = q . rel_k : per-head A = qkvb col-slice, K=128 (nt=2)
    gemm128<<<dim3(1, 4, NBH), 256, 0, stream>>>(
        qkvb, relkT, qr, nullptr, nullptr,
        NDK, 3 * ND, NDK, QRLD,
        (long)NS * 3 * ND, NDK, NH,
        0, 0, 1,
        (long)NS * QRLD, 1, 0, 0);

    // scores = q @ k^T (per-head col-slices of qkvb, nt=2)
    gemm128<<<dim3(4, 4, NBH), 256, 0, stream>>>(
        qkvb, qkvb + ND, scoresb, nullptr, nullptr,
        NDK, 3 * ND, 3 * ND, NS,
        (long)NS * 3 * ND, NDK, NH,
        (long)NS * 3 * ND, NDK, NH,
        (long)NS * NS, 1, 0, 0);

    softmax_rel<<<dim3(NS, NH, NB), 256, 0, stream>>>(
        scoresb, qr, relation, mask, attnb, attnR, loss_part, sep_p);

    // ctx = attn @ v : split-K x4 (Ksp=128, nt=2), batch 16
    gemm128<<<dim3(1, 4, NBH * 4), 256, 0, stream>>>(
        attnb, vt, ctxPart, nullptr, nullptr,
        128, NS, NS, NDK,
        (long)NS * NS, 0, 1,
        (long)NDK * NS, 0, 1,
        (long)NS * NDK, 4, (long)NBH * NS * NDK, 0);

    ctx_reduce<<<4096, 256, 0, stream>>>(ctxPart, attnR, relvT, ctxm);

    // attn_out partials: ctxm @ Wo, split-K x4 (Ksp=256, nt=4)
    gemm128<<<dim3(8, 8, 4), 256, 0, stream>>>(
        ctxm, WoT, woPart, nullptr, nullptr,
        256, ND, ND, ND,
        0, 0, 1, 0, 0, 1,
        0, 4, (long)BSROWS * ND, 0);

    wo_reduce<<<1024, 256, 0, stream>>>(woPart, x, bo, out);

    ln_bf16<<<BSROWS, 256, 0, stream>>>(out, ln2g, ln2b, h2);

    // FFN1: relu(h2 @ W1 + b1) -> F1 bf16 [1024,4096] (nt=16)
    gemm128<<<dim3(32, 8, 1), 256, 0, stream>>>(
        h2, W1T, nullptr, F1, b1,
        ND, ND, ND, NDFF,
        0, 0, 1, 0, 0, 1, 0, 1, 0, 1);

    // FFN2 partials: F1 @ W2, split-K x8 (Ksp=512, nt=8)
    gemm128<<<dim3(8, 8, 8), 256, 0, stream>>>(
        F1, W2T, f2Part, nullptr, nullptr,
        512, NDFF, NDFF, ND,
        0, 0, 1, 0, 0, 1,
        0, 8, (long)BSROWS * ND, 0);

    ffn2_reduce<<<1024, 256, 0, stream>>>(f2Part, b2, out);

    finalize_loss<<<1, 256, 0, stream>>>(loss_part, hist, sep_p, out_loss);
}